// Round 1
// baseline (60.130 us; speedup 1.0000x reference)
//
#include <hip/hip_runtime.h>
#include <math.h>

#define IMG_H 512
#define IMG_W 512
#define TILE 64
#define SRC_DIM 68   // TILE + 4 (halo 2 each side)
#define BLUR_DIM 66  // TILE + 2 (halo 1 each side)

__device__ __forceinline__ int reflect101(int i, int n) {
    if (i < 0) i = -i;
    if (i >= n) i = 2 * n - 2 - i;
    return i;
}

__global__ __launch_bounds__(256) void lap_fused_kernel(const float* __restrict__ in,
                                                        float* __restrict__ out) {
    __shared__ float s_src[SRC_DIM][SRC_DIM];
    __shared__ float s_blur[BLUR_DIM][BLUR_DIM];

    const int img = blockIdx.z;
    const int ty0 = blockIdx.y * TILE;
    const int tx0 = blockIdx.x * TILE;
    const float* __restrict__ ip = in + (size_t)img * IMG_H * IMG_W;
    float* __restrict__ op = out + (size_t)img * IMG_H * IMG_W;
    const int tid = threadIdx.x;

    // Stage 1: load + quantize src tile (reflect_101 halo of 2)
    for (int i = tid; i < SRC_DIM * SRC_DIM; i += 256) {
        int ly = i / SRC_DIM;
        int lx = i - ly * SRC_DIM;
        int gy = reflect101(ty0 + ly - 2, IMG_H);
        int gx = reflect101(tx0 + lx - 2, IMG_W);
        float v = ip[gy * IMG_W + gx];
        v = fminf(fmaxf(v * 255.0f, 0.0f), 255.0f);
        s_src[ly][lx] = floorf(v);   // uint8 quantization, exact in fp32
    }
    __syncthreads();

    // Stage 2: 3x3 Gaussian [1,2,1]^2 / 16, round-half-even (matches jnp.round)
    for (int i = tid; i < BLUR_DIM * BLUR_DIM; i += 256) {
        int ly = i / BLUR_DIM;
        int lx = i - ly * BLUR_DIM;
        int sy = ly + 1, sx = lx + 1;   // center in src-tile coords
        float sum =
              s_src[sy-1][sx-1] + 2.0f * s_src[sy-1][sx] + s_src[sy-1][sx+1]
            + 2.0f * s_src[sy][sx-1] + 4.0f * s_src[sy][sx] + 2.0f * s_src[sy][sx+1]
            + s_src[sy+1][sx-1] + 2.0f * s_src[sy+1][sx] + s_src[sy+1][sx+1];
        // sum <= 4080 (integer, exact); *0.0625 exact; rintf = round-half-even
        s_blur[ly][lx] = rintf(sum * 0.0625f);
    }
    __syncthreads();

    // Stage 3: Laplacian [[2,0,2],[0,-8,0],[2,0,2]] + |.| + clip; float4 stores
    const int tx = (tid & 15) * 4;   // 0,4,...,60
    const int ty = tid >> 4;         // 0..15
    #pragma unroll
    for (int r = 0; r < 4; ++r) {
        int y = ty + r * 16;   // 0..63
        int by = y + 1;        // blur-tile coords
        float4 o;
        float* po = (float*)&o;
        #pragma unroll
        for (int c = 0; c < 4; ++c) {
            int bx = tx + c + 1;
            float lap = 2.0f * (s_blur[by-1][bx-1] + s_blur[by-1][bx+1]
                              + s_blur[by+1][bx-1] + s_blur[by+1][bx+1])
                      - 8.0f * s_blur[by][bx];
            po[c] = fminf(fabsf(lap), 255.0f);   // integer-valued: round is a no-op
        }
        *(float4*)&op[(size_t)(ty0 + y) * IMG_W + tx0 + tx] = o;
    }
}

extern "C" void kernel_launch(void* const* d_in, const int* in_sizes, int n_in,
                              void* d_out, int out_size, void* d_ws, size_t ws_size,
                              hipStream_t stream) {
    const float* x = (const float*)d_in[0];
    float* out = (float*)d_out;
    const int n_img = 32 * 3;  // B*C
    dim3 grid(IMG_W / TILE, IMG_H / TILE, n_img);
    dim3 block(256);
    lap_fused_kernel<<<grid, block, 0, stream>>>(x, out);
}

// Round 2
// 50.403 us; speedup vs baseline: 1.1930x; 1.1930x over previous
//
#include <hip/hip_runtime.h>
#include <math.h>

#define IMG_H 512
#define IMG_W 512
#define TW 64
#define TH 32
#define SRC_ROWS 36     // TH + 4 (halo 2 each side)
#define SRC_STRIDE 72   // 64 + 8 (aligned float4 window, gx = tx0-4 .. tx0+67)
#define BLUR_ROWS 34    // TH + 2
#define BLUR_STRIDE 72

__device__ __forceinline__ int reflect101(int i, int n) {
    if (i < 0) i = -i;
    if (i >= n) i = 2 * n - 2 - i;
    return i;
}

__device__ __forceinline__ float quant(float v) {
    // uint8 quantization: floor(clip(v*255, 0, 255)) — exact in fp32
    return floorf(fminf(fmaxf(v * 255.0f, 0.0f), 255.0f));
}

__global__ __launch_bounds__(256, 8) void lap_fused(const float* __restrict__ in,
                                                    float* __restrict__ out) {
    __shared__ float s_src[SRC_ROWS][SRC_STRIDE];    // 10368 B
    __shared__ float s_blur[BLUR_ROWS][BLUR_STRIDE]; //  9792 B  (19.7 KB total -> 8 blocks/CU)

    const int img = blockIdx.z;
    const int ty0 = blockIdx.y * TH;
    const int tx0 = blockIdx.x * TW;
    const float* __restrict__ ip = in + (size_t)img * (IMG_H * IMG_W);
    float* __restrict__ op = out + (size_t)img * (IMG_H * IMG_W);
    const int tid = threadIdx.x;

    // interior-in-x blocks can use aligned float4 global loads for the whole window
    const bool xvec = (tx0 >= 4) && (tx0 + 68 <= IMG_W);

    // ---- Stage 1: load + quantize. 36 rows x 18 float4 (cols gx = tx0-4 .. tx0+67)
    for (int i = tid; i < SRC_ROWS * 18; i += 256) {
        int r = i / 18;
        int c4 = i - r * 18;
        int gy = reflect101(ty0 + r - 2, IMG_H);
        const float* rowp = ip + (size_t)gy * IMG_W;
        float4 v;
        if (xvec) {
            v = *(const float4*)(rowp + (tx0 - 4 + 4 * c4));
        } else {
            float* pv = (float*)&v;
            #pragma unroll
            for (int k = 0; k < 4; ++k) {
                int gx = reflect101(tx0 - 4 + 4 * c4 + k, IMG_W);
                pv[k] = rowp[gx];
            }
        }
        float4 q;
        q.x = quant(v.x); q.y = quant(v.y); q.z = quant(v.z); q.w = quant(v.w);
        *(float4*)&s_src[r][4 * c4] = q;
    }
    __syncthreads();

    // ---- Stage 2: separable Gaussian, 4 outputs/thread-iter, float4 LDS I/O.
    // s_blur[r][c] = blur at (ty0 + r - 1, tx0 + c - 1); needs s_src rows r..r+2, cols c+2..c+4
    for (int i = tid; i < BLUR_ROWS * 17; i += 256) {
        int r = i / 17;
        int g = i - r * 17;
        int cb = 4 * g;
        float4 a0 = *(const float4*)&s_src[r][cb];
        float4 b0 = *(const float4*)&s_src[r][cb + 4];
        float4 a1 = *(const float4*)&s_src[r + 1][cb];
        float4 b1 = *(const float4*)&s_src[r + 1][cb + 4];
        float4 a2 = *(const float4*)&s_src[r + 2][cb];
        float4 b2 = *(const float4*)&s_src[r + 2][cb + 4];
        // vertical [1,2,1] at src col cb+2+j, j=0..5
        float vs0 = a0.z + 2.0f * a1.z + a2.z;
        float vs1 = a0.w + 2.0f * a1.w + a2.w;
        float vs2 = b0.x + 2.0f * b1.x + b2.x;
        float vs3 = b0.y + 2.0f * b1.y + b2.y;
        float vs4 = b0.z + 2.0f * b1.z + b2.z;
        float vs5 = b0.w + 2.0f * b1.w + b2.w;
        // horizontal [1,2,1], /16 exact, round-half-even == jnp.round; clip 0..255 is a no-op
        float4 o;
        o.x = rintf((vs0 + 2.0f * vs1 + vs2) * 0.0625f);
        o.y = rintf((vs1 + 2.0f * vs2 + vs3) * 0.0625f);
        o.z = rintf((vs2 + 2.0f * vs3 + vs4) * 0.0625f);
        o.w = rintf((vs3 + 2.0f * vs4 + vs5) * 0.0625f);
        *(float4*)&s_blur[r][cb] = o;
    }
    __syncthreads();

    // ---- Stage 3: Laplacian [[2,0,2],[0,-8,0],[2,0,2]], |.|, clip; float4 out
    // output (yy, xb+j): blur col = x+1, rows yy..yy+2 of s_blur
    const int xb = (tid & 15) * 4;
    const int y0 = tid >> 4;
    #pragma unroll
    for (int rr = 0; rr < 2; ++rr) {
        int yy = y0 + 16 * rr;
        float4 t0 = *(const float4*)&s_blur[yy][xb];
        float4 t1 = *(const float4*)&s_blur[yy][xb + 4];
        float4 m0 = *(const float4*)&s_blur[yy + 1][xb];
        float4 m1 = *(const float4*)&s_blur[yy + 1][xb + 4];
        float4 c0 = *(const float4*)&s_blur[yy + 2][xb];
        float4 c1 = *(const float4*)&s_blur[yy + 2][xb + 4];
        // h = (t[j]+t[j+2]+b[j]+b[j+2]) - 4*m[j+1]; out = min(2|h|, 255)  (integer-exact)
        float4 o;
        float h;
        h = (t0.x + t0.z + c0.x + c0.z) - 4.0f * m0.y;
        o.x = fminf(2.0f * fabsf(h), 255.0f);
        h = (t0.y + t0.w + c0.y + c0.w) - 4.0f * m0.z;
        o.y = fminf(2.0f * fabsf(h), 255.0f);
        h = (t0.z + t1.x + c0.z + c1.x) - 4.0f * m0.w;
        o.z = fminf(2.0f * fabsf(h), 255.0f);
        h = (t0.w + t1.y + c0.w + c1.y) - 4.0f * m1.x;
        o.w = fminf(2.0f * fabsf(h), 255.0f);
        *(float4*)&op[(size_t)(ty0 + yy) * IMG_W + tx0 + xb] = o;
    }
}

extern "C" void kernel_launch(void* const* d_in, const int* in_sizes, int n_in,
                              void* d_out, int out_size, void* d_ws, size_t ws_size,
                              hipStream_t stream) {
    const float* x = (const float*)d_in[0];
    float* out = (float*)d_out;
    dim3 grid(IMG_W / TW, IMG_H / TH, 96);  // 8 x 16 x (32*3)
    dim3 block(256);
    lap_fused<<<grid, block, 0, stream>>>(x, out);
}

// Round 3
// 46.218 us; speedup vs baseline: 1.3010x; 1.0905x over previous
//
#include <hip/hip_runtime.h>
#include <math.h>

#define IMG_H 512
#define IMG_W 512
#define TW 256
#define TH 32
#define SRC_ROWS 36      // TH + 4 (src halo 2 each side)
#define SRC_SLOTS 66     // (TW+8)/4 uint slots; cols gx = tx0-4 .. tx0+259

__device__ __forceinline__ int reflect101(int i, int n) {
    if (i < 0) i = -i;
    if (i >= n) i = 2 * n - 2 - i;
    return i;
}

__device__ __forceinline__ unsigned int quant(float v) {
    // uint8 quantization: floor(clip(v*255, 0, 255)) — exact
    return (unsigned int)floorf(fminf(fmaxf(v * 255.0f, 0.0f), 255.0f));
}

// unpack src cols (local f4-window offset 2..9) from 3 packed uint slots
__device__ __forceinline__ void unpack_row(const unsigned int* __restrict__ row, int cx,
                                           float f[8]) {
    unsigned int u0 = row[cx], u1 = row[cx + 1], u2 = row[cx + 2];
    f[0] = (float)((u0 >> 16) & 0xffu);   // v_cvt_f32_ubyte2
    f[1] = (float)((u0 >> 24) & 0xffu);
    f[2] = (float)(u1 & 0xffu);
    f[3] = (float)((u1 >> 8) & 0xffu);
    f[4] = (float)((u1 >> 16) & 0xffu);
    f[5] = (float)((u1 >> 24) & 0xffu);
    f[6] = (float)(u2 & 0xffu);
    f[7] = (float)((u2 >> 8) & 0xffu);
}

// 3x3 Gaussian [1,2,1]^2/16 over src cols f[0..7] -> blur cols bl[0..5]
__device__ __forceinline__ void blur_row(const float a[8], const float b[8], const float c[8],
                                         float bl[6]) {
    float cs[8];
    #pragma unroll
    for (int j = 0; j < 8; ++j) cs[j] = a[j] + 2.0f * b[j] + c[j];
    #pragma unroll
    for (int j = 0; j < 6; ++j)
        bl[j] = rintf((cs[j] + 2.0f * cs[j + 1] + cs[j + 2]) * 0.0625f);
}

__global__ __launch_bounds__(256, 4) void lap_fused(const float* __restrict__ in,
                                                    float* __restrict__ out) {
    __shared__ unsigned int s_src[SRC_ROWS][SRC_SLOTS];  // 9504 B

    const int img = blockIdx.z;
    const int ty0 = blockIdx.y * TH;
    const int tx0 = blockIdx.x * TW;
    const float* __restrict__ ip = in + (size_t)img * (IMG_H * IMG_W);
    float* __restrict__ op = out + (size_t)img * (IMG_H * IMG_W);
    const int tid = threadIdx.x;

    // ---- Stage 1: load + quantize + pack uchar4 -> LDS
    for (int i = tid; i < SRC_ROWS * SRC_SLOTS; i += 256) {
        int r = i / SRC_SLOTS;
        int j = i - r * SRC_SLOTS;
        int gy = reflect101(ty0 + r - 2, IMG_H);
        int gx0 = tx0 - 4 + 4 * j;
        const float* rowp = ip + (size_t)gy * IMG_W;
        float4 v;
        if (gx0 >= 0 && gx0 + 3 < IMG_W) {
            v = *(const float4*)(rowp + gx0);
        } else {
            float* pv = (float*)&v;
            #pragma unroll
            for (int k = 0; k < 4; ++k) pv[k] = rowp[reflect101(gx0 + k, IMG_W)];
        }
        unsigned int p = quant(v.x) | (quant(v.y) << 8) | (quant(v.z) << 16) | (quant(v.w) << 24);
        s_src[r][j] = p;
    }
    __syncthreads();

    // ---- Stage 2+3: register rolling-window blur + Laplacian
    const int cx = tid & 63;         // col group: out cols xo..xo+3
    const int rw = tid >> 6;         // row band: out rows y0..y0+7
    const int xo = tx0 + 4 * cx;
    const int lr0 = 8 * rw;          // LDS row holding src row y0-2

    float s[3][8];
    unpack_row(&s_src[lr0 + 0][0], cx, s[0]);  // src y0-2
    unpack_row(&s_src[lr0 + 1][0], cx, s[1]);  // src y0-1
    unpack_row(&s_src[lr0 + 2][0], cx, s[2]);  // src y0
    float bl[3][6];
    blur_row(s[0], s[1], s[2], bl[0]);         // blur y0-1
    unpack_row(&s_src[lr0 + 3][0], cx, s[0]);  // src y0+1
    blur_row(s[1], s[2], s[0], bl[1]);         // blur y0

    #pragma unroll
    for (int k = 0; k < 8; ++k) {
        // load src row y0+2+k into the slot holding the no-longer-needed row
        unpack_row(&s_src[lr0 + 4 + k][0], cx, s[(k + 1) % 3]);
        // blur(y0+1+k) from src rows (y0+k, y0+k+1, y0+k+2)
        blur_row(s[(k + 2) % 3], s[k % 3], s[(k + 1) % 3], bl[(k + 2) % 3]);

        const float* bm1 = bl[k % 3];        // blur(y0+k-1)
        const float* b0  = bl[(k + 1) % 3];  // blur(y0+k)
        const float* bp1 = bl[(k + 2) % 3];  // blur(y0+k+1)
        float4 o;
        float* po = (float*)&o;
        #pragma unroll
        for (int d = 0; d < 4; ++d) {
            float h = (bm1[d] + bm1[d + 2] + bp1[d] + bp1[d + 2]) - 4.0f * b0[d + 1];
            po[d] = fminf(2.0f * fabsf(h), 255.0f);  // integer-exact
        }
        *(float4*)&op[(size_t)(ty0 + 8 * rw + k) * IMG_W + xo] = o;
    }
}

extern "C" void kernel_launch(void* const* d_in, const int* in_sizes, int n_in,
                              void* d_out, int out_size, void* d_ws, size_t ws_size,
                              hipStream_t stream) {
    const float* x = (const float*)d_in[0];
    float* out = (float*)d_out;
    dim3 grid(IMG_W / TW, IMG_H / TH, 96);  // 2 x 16 x (32*3)
    dim3 block(256);
    lap_fused<<<grid, block, 0, stream>>>(x, out);
}

// Round 4
// 45.939 us; speedup vs baseline: 1.3089x; 1.0061x over previous
//
#include <hip/hip_runtime.h>
#include <math.h>

#define IMG_H 512
#define IMG_W 512
#define TW 256
#define TH 32
#define SRC_ROWS 36      // TH + 4 (src halo 2 each side)
#define SRC_SLOTS 66     // (TW+8)/4 uint slots; cols gx = tx0-4 .. tx0+259

__device__ __forceinline__ int reflect101(int i, int n) {
    if (i < 0) i = -i;
    if (i >= n) i = 2 * n - 2 - i;
    return i;
}

__device__ __forceinline__ unsigned int quant(float v) {
    // uint8 quantization: floor(clip(v*255, 0, 255)) — exact
    return (unsigned int)floorf(fminf(fmaxf(v * 255.0f, 0.0f), 255.0f));
}

// Unpack src cols xo-2..xo+5 (8 cols) from LDS row `row` into named floats F0..F7.
// Slot cx bytes 2,3 = cols xo-2,xo-1; slot cx+1 = xo..xo+3; slot cx+2 bytes 0,1 = xo+4,xo+5.
#define UNPACK(row, F) do {                                                   \
    unsigned int u0_ = s_src[row][cx];                                        \
    unsigned int u1_ = s_src[row][cx + 1];                                    \
    unsigned int u2_ = s_src[row][cx + 2];                                    \
    F##0 = (float)((u0_ >> 16) & 0xffu);                                      \
    F##1 = (float)(u0_ >> 24);                                                \
    F##2 = (float)(u1_ & 0xffu);                                              \
    F##3 = (float)((u1_ >> 8) & 0xffu);                                       \
    F##4 = (float)((u1_ >> 16) & 0xffu);                                      \
    F##5 = (float)(u1_ >> 24);                                                \
    F##6 = (float)(u2_ & 0xffu);                                              \
    F##7 = (float)((u2_ >> 8) & 0xffu);                                       \
} while (0)

// 3x3 Gaussian [1,2,1]^2/16: BL_j = blur col xo-1+j (j=0..5) from src rows A,B,C.
// All sums are small ints (<=4080), exact in fp32; rintf == round-half-even == jnp.round.
#define BLUR(A, B, C, BL) do {                                                \
    float c0_ = A##0 + 2.0f * B##0 + C##0;                                    \
    float c1_ = A##1 + 2.0f * B##1 + C##1;                                    \
    float c2_ = A##2 + 2.0f * B##2 + C##2;                                    \
    float c3_ = A##3 + 2.0f * B##3 + C##3;                                    \
    float c4_ = A##4 + 2.0f * B##4 + C##4;                                    \
    float c5_ = A##5 + 2.0f * B##5 + C##5;                                    \
    float c6_ = A##6 + 2.0f * B##6 + C##6;                                    \
    float c7_ = A##7 + 2.0f * B##7 + C##7;                                    \
    BL##0 = rintf((c0_ + 2.0f * c1_ + c2_) * 0.0625f);                        \
    BL##1 = rintf((c1_ + 2.0f * c2_ + c3_) * 0.0625f);                        \
    BL##2 = rintf((c2_ + 2.0f * c3_ + c4_) * 0.0625f);                        \
    BL##3 = rintf((c3_ + 2.0f * c4_ + c5_) * 0.0625f);                        \
    BL##4 = rintf((c4_ + 2.0f * c5_ + c6_) * 0.0625f);                        \
    BL##5 = rintf((c5_ + 2.0f * c6_ + c7_) * 0.0625f);                        \
} while (0)

// Laplacian [[2,0,2],[0,-8,0],[2,0,2]] on blur rows BM (y-1), B0 (y), BP (y+1);
// out col xo+d uses BL indices d, d+1, d+2. out = min(|lap|,255), lap = 2*h.
#define LAP_STORE(BM, B0, BP, yy) do {                                        \
    float4 o_;                                                                \
    float h_;                                                                 \
    h_ = (BM##0 + BM##2 + BP##0 + BP##2) - 4.0f * B0##1;                      \
    o_.x = fminf(2.0f * fabsf(h_), 255.0f);                                   \
    h_ = (BM##1 + BM##3 + BP##1 + BP##3) - 4.0f * B0##2;                      \
    o_.y = fminf(2.0f * fabsf(h_), 255.0f);                                   \
    h_ = (BM##2 + BM##4 + BP##2 + BP##4) - 4.0f * B0##3;                      \
    o_.z = fminf(2.0f * fabsf(h_), 255.0f);                                   \
    h_ = (BM##3 + BM##5 + BP##3 + BP##5) - 4.0f * B0##4;                      \
    o_.w = fminf(2.0f * fabsf(h_), 255.0f);                                   \
    *(float4*)&op[(size_t)(ty0 + (yy)) * IMG_W + xo] = o_;                    \
} while (0)

__global__ __launch_bounds__(256, 4) void lap_fused(const float* __restrict__ in,
                                                    float* __restrict__ out) {
    __shared__ unsigned int s_src[SRC_ROWS][SRC_SLOTS];  // 9504 B

    const int img = blockIdx.z;
    const int ty0 = blockIdx.y * TH;
    const int tx0 = blockIdx.x * TW;
    const float* __restrict__ ip = in + (size_t)img * (IMG_H * IMG_W);
    float* __restrict__ op = out + (size_t)img * (IMG_H * IMG_W);
    const int tid = threadIdx.x;

    // ---- Stage 1: load + quantize + pack uchar4 -> LDS
    for (int i = tid; i < SRC_ROWS * SRC_SLOTS; i += 256) {
        int r = i / SRC_SLOTS;
        int j = i - r * SRC_SLOTS;
        int gy = reflect101(ty0 + r - 2, IMG_H);
        int gx0 = tx0 - 4 + 4 * j;
        const float* rowp = ip + (size_t)gy * IMG_W;
        float4 v;
        if (gx0 >= 0 && gx0 + 3 < IMG_W) {
            v = *(const float4*)(rowp + gx0);
        } else {
            float* pv = (float*)&v;
            #pragma unroll
            for (int k = 0; k < 4; ++k) pv[k] = rowp[reflect101(gx0 + k, IMG_W)];
        }
        s_src[r][j] = quant(v.x) | (quant(v.y) << 8) | (quant(v.z) << 16) | (quant(v.w) << 24);
    }
    __syncthreads();

    // ---- Stage 2+3: straight-line register rolling window (NO arrays -> no scratch)
    const int cx = tid & 63;   // col group: out cols xo..xo+3
    const int rw = tid >> 6;   // row band: out rows y0..y0+7
    const int xo = tx0 + 4 * cx;
    const int lr0 = 8 * rw;    // LDS row of src row y0-2

    float sA0, sA1, sA2, sA3, sA4, sA5, sA6, sA7;
    float sB0, sB1, sB2, sB3, sB4, sB5, sB6, sB7;
    float sC0, sC1, sC2, sC3, sC4, sC5, sC6, sC7;
    float bP0, bP1, bP2, bP3, bP4, bP5;
    float bQ0, bQ1, bQ2, bQ3, bQ4, bQ5;
    float bR0, bR1, bR2, bR3, bR4, bR5;

    UNPACK(lr0 + 0, sA);
    UNPACK(lr0 + 1, sB);
    UNPACK(lr0 + 2, sC);
    BLUR(sA, sB, sC, bP);            // blur(y0-1)
    UNPACK(lr0 + 3, sA);
    BLUR(sB, sC, sA, bQ);            // blur(y0)

    const int yb = 8 * rw;
    UNPACK(lr0 + 4, sB);  BLUR(sC, sA, sB, bR);  LAP_STORE(bP, bQ, bR, yb + 0);
    UNPACK(lr0 + 5, sC);  BLUR(sA, sB, sC, bP);  LAP_STORE(bQ, bR, bP, yb + 1);
    UNPACK(lr0 + 6, sA);  BLUR(sB, sC, sA, bQ);  LAP_STORE(bR, bP, bQ, yb + 2);
    UNPACK(lr0 + 7, sB);  BLUR(sC, sA, sB, bR);  LAP_STORE(bP, bQ, bR, yb + 3);
    UNPACK(lr0 + 8, sC);  BLUR(sA, sB, sC, bP);  LAP_STORE(bQ, bR, bP, yb + 4);
    UNPACK(lr0 + 9, sA);  BLUR(sB, sC, sA, bQ);  LAP_STORE(bR, bP, bQ, yb + 5);
    UNPACK(lr0 + 10, sB); BLUR(sC, sA, sB, bR);  LAP_STORE(bP, bQ, bR, yb + 6);
    UNPACK(lr0 + 11, sC); BLUR(sA, sB, sC, bP);  LAP_STORE(bQ, bR, bP, yb + 7);
}

extern "C" void kernel_launch(void* const* d_in, const int* in_sizes, int n_in,
                              void* d_out, int out_size, void* d_ws, size_t ws_size,
                              hipStream_t stream) {
    const float* x = (const float*)d_in[0];
    float* out = (float*)d_out;
    dim3 grid(IMG_W / TW, IMG_H / TH, 96);  // 2 x 16 x (32*3)
    dim3 block(256);
    lap_fused<<<grid, block, 0, stream>>>(x, out);
}